// Round 5
// baseline (441.631 us; speedup 1.0000x reference)
//
#include <hip/hip_runtime.h>
#include <math.h>

#define B_ 4
#define K_ 4096
#define C_ 256
#define H_ 128
#define RAD 5
#define ROWS 8
#define BAND (ROWS + 2 * RAD)   // 18 tokens staged per block
#define NB   (2 * RAD + 1)      // 11 band entries per row

typedef float floatx4 __attribute__((ext_vector_type(4)));

// ---------------- Kernel 1: per-batch column-sum partials ----------------
// 512 blocks x 256 thr; block sums 32 consecutive rows -> partial[blk][256] in ws.
__global__ __launch_bounds__(256) void colsum_partial(
    const float* __restrict__ x, float* __restrict__ partial)
{
    const int tid = threadIdx.x;
    const int blk = blockIdx.x;
    const float* base = x + (size_t)blk * 32 * C_ + tid;
    float a0 = 0.f, a1 = 0.f, a2 = 0.f, a3 = 0.f;
    #pragma unroll
    for (int kk = 0; kk < 32; kk += 4) {
        a0 += base[(size_t)(kk + 0) * C_];
        a1 += base[(size_t)(kk + 1) * C_];
        a2 += base[(size_t)(kk + 2) * C_];
        a3 += base[(size_t)(kk + 3) * C_];
    }
    partial[(size_t)blk * C_ + tid] = (a0 + a1) + (a2 + a3);
}

// ---------------- Kernel 2: fused score + softmax + outputs ----------------
// 2048 blocks x 256 thr; block owns 8 query rows of one batch.
// Phase A: redundantly compute MLP scores for the 18-token band
//          (thread = (hidden h = tid&127, token-group g = tid>>7)).
// Phase B: threads 0..7 -> per-row softmax scalars (band weights + w_off).
// Phase C: all threads reduce Ssum[channel] from the 128 partials.
// Phase D: weighted rows (x reads while L2 warm), then 131 KB weights stream.
__global__ __launch_bounds__(256, 4) void fused_attn(
    const float* __restrict__ x, const float* __restrict__ W1,
    const float* __restrict__ b1, const float* __restrict__ W2,
    const float* __restrict__ b2, const float* __restrict__ partial,
    float* __restrict__ out)
{
    const int tid = threadIdx.x;
    const int blk = blockIdx.x;                   // b*(K_/ROWS) + tile
    const int b  = blk >> 9;                      // K_/ROWS = 512
    const int i0 = (blk & 511) * ROWS;

    const int j0t = max(0, i0 - RAD);
    const int j1t = min(K_ - 1, i0 + ROWS - 1 + RAD);
    const int ntok = j1t - j0t + 1;               // <= 18

    __shared__ float red[4][9];
    __shared__ float sb[BAND];
    __shared__ float wb[ROWS][NB];
    __shared__ float woff[ROWS];
    __shared__ float ssum[C_];

    // ---- Phase A: band scores. g=0 -> tokens 0..8, g=1 -> tokens 9..17 ----
    {
        const int h = tid & 127;
        const int g = tid >> 7;
        const float* xbase = x + ((size_t)b * K_ + j0t) * C_;
        const float* xp[9];
        #pragma unroll
        for (int t = 0; t < 9; ++t) {
            int tt = g * 9 + t;
            if (tt > ntok - 1) tt = ntok - 1;     // clamp: extra scores unused
            xp[t] = xbase + (size_t)tt * C_;
        }
        float acc[9];
        float binit = b1[h];
        #pragma unroll
        for (int t = 0; t < 9; ++t) acc[t] = binit;

        for (int c = 0; c < C_; c += 4) {
            float w0 = W1[(c + 0) * H_ + h];
            float w1 = W1[(c + 1) * H_ + h];
            float w2 = W1[(c + 2) * H_ + h];
            float w3 = W1[(c + 3) * H_ + h];
            #pragma unroll
            for (int t = 0; t < 9; ++t) {
                floatx4 xv = *(const floatx4*)(xp[t] + c);   // wave-uniform -> broadcast
                acc[t] = fmaf(xv.x, w0, acc[t]);
                acc[t] = fmaf(xv.y, w1, acc[t]);
                acc[t] = fmaf(xv.z, w2, acc[t]);
                acc[t] = fmaf(xv.w, w3, acc[t]);
            }
        }
        float w2v = W2[h];
        const int w = tid >> 6;                   // wave id 0..3
        #pragma unroll
        for (int t = 0; t < 9; ++t) {
            float p = tanhf(acc[t]) * w2v;
            #pragma unroll
            for (int off = 32; off > 0; off >>= 1) p += __shfl_down(p, off);
            if ((tid & 63) == 0) red[w][t] = p;
        }
    }
    __syncthreads();
    if (tid < BAND) {
        const int gg = tid / 9, t9 = tid % 9;
        sb[tid] = red[2 * gg][t9] + red[2 * gg + 1][t9] + b2[0];
    }
    __syncthreads();

    // ---- Phase C: Ssum[channel tid] from 128 partial chunks (coalesced) ----
    float ss = 0.f;
    {
        const float* pb = partial + (size_t)b * 128 * C_ + tid;
        for (int ch = 0; ch < 128; ++ch) ss += pb[(size_t)ch * C_];
    }

    // ---- Phase B: softmax scalars, threads 0..7 (one per row) ----
    if (tid < ROWS) {
        const int i = i0 + tid;
        const int j0 = max(0, i - RAD), j1 = min(K_ - 1, i + RAD);
        const int nb = j1 - j0 + 1;
        float m = 0.f;                            // off-band score 0 => max >= 0
        for (int j = j0; j <= j1; ++j) m = fmaxf(m, sb[j - j0t]);
        float e0 = expf(-m);
        float D = (float)(K_ - nb) * e0;
        for (int j = j0; j <= j1; ++j) {
            float e = expf(sb[j - j0t] - m);
            wb[tid][j - j0] = e;
            D += e;
        }
        float inv = 1.0f / D;
        for (int jj = 0; jj < nb; ++jj) wb[tid][jj] *= inv;
        woff[tid] = e0 * inv;
    }
    ssum[tid] = ss;
    __syncthreads();

    // ---- Phase D1: weighted rows (vectorized float4), before the big store stream ----
    // thread t: f4-channel ct = t&63, rows (t>>6) and (t>>6)+4
    {
        const int ct = tid & 63;
        const floatx4 sc4 = ((const floatx4*)ssum)[ct];
        #pragma unroll
        for (int rr = 0; rr < 2; ++rr) {
            const int r = (tid >> 6) + rr * 4;
            const int i = i0 + r;
            const int j0 = max(0, i - RAD), j1 = min(K_ - 1, i + RAD);
            const float wo = woff[r];
            floatx4 acc4 = { wo * sc4.x, wo * sc4.y, wo * sc4.z, wo * sc4.w };
            const floatx4* xr = (const floatx4*)(x + ((size_t)b * K_) * C_) + ct;
            for (int j = j0; j <= j1; ++j) {
                const float wd = wb[r][j - j0] - wo;
                floatx4 xv = xr[(size_t)j * (C_ / 4)];
                acc4.x = fmaf(wd, xv.x, acc4.x);
                acc4.y = fmaf(wd, xv.y, acc4.y);
                acc4.z = fmaf(wd, xv.z, acc4.z);
                acc4.w = fmaf(wd, xv.w, acc4.w);
            }
            ((floatx4*)(out + ((size_t)b * K_ + i) * C_))[ct] = acc4;
        }
    }

    // ---- Phase D2: weights rows, 8 x 16 KB contiguous streams ----
    #pragma unroll
    for (int r = 0; r < ROWS; ++r) {
        const int i = i0 + r;
        const int j0 = max(0, i - RAD), j1 = min(K_ - 1, i + RAD);
        const float wo = woff[r];
        floatx4* wrow4 = (floatx4*)(out + (size_t)B_ * K_ * C_ + ((size_t)b * K_ + i) * K_);
        #pragma unroll
        for (int q = 0; q < 4; ++q) {
            const int f = tid + 256 * q;
            const int jb = f * 4;
            floatx4 v = { wo, wo, wo, wo };
            if (jb + 3 >= j0 && jb <= j1) {       // touches band (rare)
                if (jb + 0 >= j0 && jb + 0 <= j1) v.x = wb[r][jb + 0 - j0];
                if (jb + 1 >= j0 && jb + 1 <= j1) v.y = wb[r][jb + 1 - j0];
                if (jb + 2 >= j0 && jb + 2 <= j1) v.z = wb[r][jb + 2 - j0];
                if (jb + 3 >= j0 && jb + 3 <= j1) v.w = wb[r][jb + 3 - j0];
            }
            wrow4[f] = v;
        }
    }
}

extern "C" void kernel_launch(void* const* d_in, const int* in_sizes, int n_in,
                              void* d_out, int out_size, void* d_ws, size_t ws_size,
                              hipStream_t stream) {
    const float* x  = (const float*)d_in[0];
    const float* W1 = (const float*)d_in[1];
    const float* b1 = (const float*)d_in[2];
    const float* W2 = (const float*)d_in[3];
    const float* b2 = (const float*)d_in[4];
    float* out = (float*)d_out;
    float* partial = (float*)d_ws;                // 512*256 floats = 512 KB

    colsum_partial<<<B_ * 128,       256, 0, stream>>>(x, partial);
    fused_attn    <<<B_ * K_ / ROWS, 256, 0, stream>>>(x, W1, b1, W2, b2, partial, out);
}

// Round 6
// 380.329 us; speedup vs baseline: 1.1612x; 1.1612x over previous
//
#include <hip/hip_runtime.h>
#include <math.h>

#define B_ 4
#define K_ 4096
#define C_ 256
#define H_ 128
#define RAD 5
#define NB (2 * RAD + 1)
#define PSTRIDE 12   // 11 band weights + woff, 48B (16B-aligned)

typedef float floatx4 __attribute__((ext_vector_type(4)));

// ws layout (floats):
//   s:       [B_*K_]          @ 0        (64 KB)
//   Ssum:    [B_*C_]          @ 16384    (4 KB)
//   partial: [512*C_]         @ 17408    (512 KB)
//   params:  [B_*K_*PSTRIDE]  @ 148480   (768 KB)

// ---------------- K1: per-token MLP score ----------------
__global__ __launch_bounds__(128) void score_kernel(
    const float* __restrict__ x, const float* __restrict__ W1,
    const float* __restrict__ b1, const float* __restrict__ W2,
    const float* __restrict__ b2, float* __restrict__ s_out)
{
    const int tid = threadIdx.x;
    const int t0 = blockIdx.x * 8;
    const float* xr[8];
    #pragma unroll
    for (int t = 0; t < 8; ++t) xr[t] = x + (size_t)(t0 + t) * C_;

    float acc[8];
    float binit = b1[tid];
    #pragma unroll
    for (int t = 0; t < 8; ++t) acc[t] = binit;

    for (int c = 0; c < C_; c += 4) {
        float w0 = W1[(c + 0) * H_ + tid];
        float w1 = W1[(c + 1) * H_ + tid];
        float w2 = W1[(c + 2) * H_ + tid];
        float w3 = W1[(c + 3) * H_ + tid];
        #pragma unroll
        for (int t = 0; t < 8; ++t) {
            floatx4 xv = *(const floatx4*)&xr[t][c];   // wave-uniform -> s_load
            acc[t] = fmaf(xv.x, w0, acc[t]);
            acc[t] = fmaf(xv.y, w1, acc[t]);
            acc[t] = fmaf(xv.z, w2, acc[t]);
            acc[t] = fmaf(xv.w, w3, acc[t]);
        }
    }

    __shared__ float red[2][8];
    float w2v = W2[tid];
    #pragma unroll
    for (int t = 0; t < 8; ++t) {
        float p = tanhf(acc[t]) * w2v;
        #pragma unroll
        for (int off = 32; off > 0; off >>= 1) p += __shfl_down(p, off);
        if ((tid & 63) == 0) red[tid >> 6][t] = p;
    }
    __syncthreads();
    if (tid < 8) s_out[t0 + tid] = red[0][tid] + red[1][tid] + b2[0];
}

// ---------------- K2a/K2b: per-batch column sums ----------------
__global__ __launch_bounds__(256) void colsum_partial(
    const float* __restrict__ x, float* __restrict__ partial)
{
    const int tid = threadIdx.x;
    const int blk = blockIdx.x;
    const float* base = x + (size_t)blk * 32 * C_ + tid;
    float a0 = 0.f, a1 = 0.f, a2 = 0.f, a3 = 0.f;
    #pragma unroll
    for (int kk = 0; kk < 32; kk += 4) {
        a0 += base[(size_t)(kk + 0) * C_];
        a1 += base[(size_t)(kk + 1) * C_];
        a2 += base[(size_t)(kk + 2) * C_];
        a3 += base[(size_t)(kk + 3) * C_];
    }
    partial[(size_t)blk * C_ + tid] = (a0 + a1) + (a2 + a3);
}

__global__ __launch_bounds__(256) void colsum_final(
    const float* __restrict__ partial, float* __restrict__ Ssum)
{
    const int tid = threadIdx.x;
    const int b = blockIdx.x;
    float acc = 0.f;
    for (int chunk = 0; chunk < 128; ++chunk)
        acc += partial[(size_t)(b * 128 + chunk) * C_ + tid];
    Ssum[b * C_ + tid] = acc;
}

// ---------------- K3: softmax params, one THREAD per row ----------------
__global__ __launch_bounds__(256) void params_kernel(
    const float* __restrict__ s, float* __restrict__ params)
{
    const int row = blockIdx.x * 256 + threadIdx.x;   // b*K_ + i
    const int b = row >> 12;
    const int i = row & (K_ - 1);
    const int j0 = max(0, i - RAD), j1 = min(K_ - 1, i + RAD);
    const int nb = j1 - j0 + 1;
    const float* srow = s + b * K_;

    float sv[NB];
    float m = 0.f;                                    // off-band score 0 => max >= 0
    #pragma unroll
    for (int jj = 0; jj < NB; ++jj) {
        // ws is large enough that srow[j0+jj] never leaves d_ws; guard the value.
        float v = (jj < nb) ? srow[j0 + jj] : 0.f;
        sv[jj] = v;
        if (jj < nb) m = fmaxf(m, v);
    }
    float e0 = expf(-m);
    float D = (float)(K_ - nb) * e0;
    float* pp = params + (size_t)row * PSTRIDE;
    #pragma unroll
    for (int jj = 0; jj < NB; ++jj) {
        float e = expf(sv[jj] - m);
        if (jj < nb) D += e;
        sv[jj] = e;
    }
    float inv = 1.0f / D;
    #pragma unroll
    for (int jj = 0; jj < NB; ++jj) pp[jj] = sv[jj] * inv;  // jj>=nb slots unread
    pp[11] = e0 * inv;
}

// ---------------- K4: pure streaming store kernel, one block per row ----------------
__global__ __launch_bounds__(256) void store_kernel(
    const float* __restrict__ x, const float* __restrict__ params,
    const float* __restrict__ Ssum, float* __restrict__ out)
{
    const int tid = threadIdx.x;
    const int row = blockIdx.x;                       // b*K_ + i
    const int b = row >> 12;
    const int i = row & (K_ - 1);
    const int j0 = max(0, i - RAD), j1 = min(K_ - 1, i + RAD);
    const int nb = j1 - j0 + 1;

    __shared__ float wbs[PSTRIDE];
    if (tid < PSTRIDE) wbs[tid] = params[(size_t)row * PSTRIDE + tid];
    __syncthreads();
    const float woff = wbs[11];

    // ---- weighted row: thread owns channel tid; <=11 coalesced 1KB x loads ----
    {
        float acc = woff * Ssum[b * C_ + tid];
        const float* xb = x + ((size_t)b * K_ + j0) * C_ + tid;
        #pragma unroll
        for (int jj = 0; jj < NB; ++jj) {
            if (jj < nb)
                acc = fmaf(wbs[jj] - woff, xb[(size_t)jj * C_], acc);
        }
        out[(size_t)row * C_ + tid] = acc;
    }

    // ---- weights row: 1024 float4, thread writes f = tid + 256q (contiguous/wave) ----
    floatx4* wrow4 = (floatx4*)(out + (size_t)B_ * K_ * C_ + (size_t)row * K_);
    #pragma unroll
    for (int q = 0; q < 4; ++q) {
        const int f = tid + 256 * q;
        const int jb = f * 4;
        floatx4 v = { woff, woff, woff, woff };
        if (jb + 3 >= j0 && jb <= j1) {               // <=3 threads touch the band
            if (jb + 0 >= j0 && jb + 0 <= j1) v.x = wbs[jb + 0 - j0];
            if (jb + 1 >= j0 && jb + 1 <= j1) v.y = wbs[jb + 1 - j0];
            if (jb + 2 >= j0 && jb + 2 <= j1) v.z = wbs[jb + 2 - j0];
            if (jb + 3 >= j0 && jb + 3 <= j1) v.w = wbs[jb + 3 - j0];
        }
        __builtin_nontemporal_store(v, wrow4 + f);    // zero-reuse stream: don't pollute L2
    }
}

extern "C" void kernel_launch(void* const* d_in, const int* in_sizes, int n_in,
                              void* d_out, int out_size, void* d_ws, size_t ws_size,
                              hipStream_t stream) {
    const float* x  = (const float*)d_in[0];
    const float* W1 = (const float*)d_in[1];
    const float* b1 = (const float*)d_in[2];
    const float* W2 = (const float*)d_in[3];
    const float* b2 = (const float*)d_in[4];
    float* out = (float*)d_out;

    float* ws      = (float*)d_ws;
    float* s       = ws;                      // 16384
    float* Ssum    = ws + 16384;              // 1024
    float* partial = ws + 17408;              // 131072
    float* params  = ws + 148480;             // 196608

    score_kernel  <<<B_ * K_ / 8,  128, 0, stream>>>(x, W1, b1, W2, b2, s);
    colsum_partial<<<B_ * 128,     256, 0, stream>>>(x, partial);
    colsum_final  <<<B_,           256, 0, stream>>>(partial, Ssum);
    params_kernel <<<B_ * K_ / 256,256, 0, stream>>>(s, params);
    store_kernel  <<<B_ * K_,      256, 0, stream>>>(x, params, Ssum, out);
}